// Round 5
// baseline (370.132 us; speedup 1.0000x reference)
//
#include <hip/hip_runtime.h>
#include <hip/hip_bf16.h>
#include <hip/hip_fp16.h>
#include <math.h>

#define D_IN   128
#define D_RNI  32
#define HID    256

typedef _Float16 half8 __attribute__((ext_vector_type(8)));
typedef float    f32x4 __attribute__((ext_vector_type(4)));

// ---------------------------------------------------------------------------
// k_prep: fused {edge dtype detect} + {3x weight transpose/cast} + {counts=0}.
// Block 0: int64 edges (values < 2^31) have all odd words zero -> mode=1.
// Blocks 1..160:   W1 (160x256 fp32) -> W1t[256][160] fp16
// Blocks 161..416: W2 (256x256)      -> W2t[256][256]
// Blocks 417..672: W_out             -> Wot[256][256]
// Blocks 673..868: counts[n] = 0     (replaces hipMemsetAsync dispatch)
// ---------------------------------------------------------------------------
__global__ void k_prep(const unsigned int* __restrict__ ew, int nwords, int* __restrict__ mode,
                       const float* __restrict__ W1, __half* __restrict__ W1t,
                       const float* __restrict__ W2, __half* __restrict__ W2t,
                       const float* __restrict__ Wo, __half* __restrict__ Wot,
                       int* __restrict__ counts, int n) {
    int b = blockIdx.x;
    if (b == 0) {
        __shared__ unsigned int red[256];
        unsigned int acc = 0;
        for (int i = threadIdx.x; i < 1024; i += 256) {
            int idx = 2 * i + 1;
            if (idx < nwords) acc |= ew[idx];
        }
        red[threadIdx.x] = acc;
        __syncthreads();
        for (int s = 128; s > 0; s >>= 1) {
            if (threadIdx.x < s) red[threadIdx.x] |= red[threadIdx.x + s];
            __syncthreads();
        }
        if (threadIdx.x == 0) *mode = (red[0] == 0u) ? 1 : 0;
        return;
    }
    const int T1 = (D_IN + D_RNI) * HID;   // 40960  (160 blocks)
    const int T2 = HID * HID;              // 65536  (256 blocks each)
    const int TW = T1 + 2 * T2;            // 172032 (672 blocks)
    int i = (b - 1) * 256 + threadIdx.x;
    if (i < T1) {
        int k = i / HID, nn = i - k * HID;
        W1t[(size_t)nn * (D_IN + D_RNI) + k] = __float2half(W1[i]);
    } else if (i < T1 + T2) {
        int j = i - T1;
        int k = j / HID, nn = j - k * HID;
        W2t[(size_t)nn * HID + k] = __float2half(W2[j]);
    } else if (i < TW) {
        int j = i - T1 - T2;
        int k = j / HID, nn = j - k * HID;
        Wot[(size_t)nn * HID + k] = __float2half(Wo[j]);
    } else {
        int j = i - TW;
        if (j < n) counts[j] = 0;
    }
}

__global__ void k_count(const unsigned int* __restrict__ ew, const int* __restrict__ mode_p,
                        int* __restrict__ counts, int e) {
    int mode = *mode_p;
    int i = blockIdx.x * 256 + threadIdx.x;
    if (i >= e) return;
    int d = mode ? (int)ew[2 * ((size_t)e + i)] : (int)ew[(size_t)e + i];
    atomicAdd(&counts[d], 1);
}

// ---------------------------------------------------------------------------
// Scan: k_scan1 produces per-1024-chunk inclusive scans + raw chunk sums;
// k_scan3 folds the (<=64-entry) chunk-sum prefix in-kernel via a wave
// reduce (no separate scan2 dispatch).
// ---------------------------------------------------------------------------
__global__ __launch_bounds__(1024) void k_scan1(const int* __restrict__ counts,
                                                int* __restrict__ incl,
                                                int* __restrict__ bsum, int n) {
    __shared__ int sd[1024];
    int t = threadIdx.x;
    int i = blockIdx.x * 1024 + t;
    int v = (i < n) ? counts[i] : 0;
    sd[t] = v;
    __syncthreads();
    for (int off = 1; off < 1024; off <<= 1) {
        int tmp = (t >= off) ? sd[t - off] : 0;
        __syncthreads();
        sd[t] += tmp;
        __syncthreads();
    }
    if (i < n) incl[i] = sd[t];
    if (t == 1023) bsum[blockIdx.x] = sd[1023];
}

__global__ void k_scan3(const int* __restrict__ counts, const int* __restrict__ incl,
                        const int* __restrict__ bsum,
                        int* __restrict__ rowptr, int* __restrict__ cursor,
                        float* __restrict__ dis, int n, int nb) {
    __shared__ int pre_s, tot_s;
    int t = threadIdx.x;
    int c = (blockIdx.x * 256) >> 10;           // this block's 1024-chunk index
    if (t < 64) {
        int v   = (t < nb) ? bsum[t] : 0;       // raw chunk sums
        int pre = (t < c)  ? v : 0;
        int tot = v;
        #pragma unroll
        for (int m = 32; m > 0; m >>= 1) {
            pre += __shfl_down(pre, m);
            tot += __shfl_down(tot, m);
        }
        if (t == 0) { pre_s = pre; tot_s = tot; }
    }
    __syncthreads();
    int i = blockIdx.x * 256 + t;
    if (i >= n) return;
    int excl = incl[i] - counts[i] + pre_s;
    rowptr[i] = excl;
    cursor[i] = excl;
    dis[i] = 1.0f / sqrtf((float)(counts[i] + 1));
    if (i == 0) rowptr[n] = tot_s;
}

__global__ void k_scatter(const unsigned int* __restrict__ ew, const int* __restrict__ mode_p,
                          int* __restrict__ cursor, int* __restrict__ csr, int e) {
    int mode = *mode_p;
    int i = blockIdx.x * 256 + threadIdx.x;
    if (i >= e) return;
    int s, d;
    if (mode) {
        s = (int)ew[2 * (size_t)i];
        d = (int)ew[2 * ((size_t)e + i)];
    } else {
        s = (int)ew[(size_t)i];
        d = (int)ew[(size_t)e + i];
    }
    int pos = atomicAdd(&cursor[d], 1);
    csr[pos] = s;
}

// ---------------------------------------------------------------------------
// fp16 MFMA GEMM: C[M x 256] = A[M x K] @ Bt^T  (Bt:[N=256][K] fp16).
// A_F32: A (and optional A2, concat along K at KA) are fp32, converted to fp16
// during LDS staging (fuses the input cast; K-split KA must be KT-aligned).
//
// 512 threads = 8 waves as 2(M)x4(N); tile 128 M x 256 N.
// LDS double-buffer -> ONE barrier per K-step; global loads for step t+1
// issued before step t's MFMAs, LDS-write after them (vmcnt wait hidden under
// MFMA). __launch_bounds__(512,4) caps VGPR at 128 -> 2 blocks/CU resident.
// LDS rows padded to 40 halves (LSTR) - verified fragment layout.
// ---------------------------------------------------------------------------
#define KT 32
#define LSTR 40
template <bool A_F32, bool ADD_BIAS, bool HALF_OUT>
__global__ __launch_bounds__(512, 4) void k_mgemm(const void* __restrict__ Av, int strideA, int KA,
                                                  const void* __restrict__ A2v, int strideA2,
                                                  const __half* __restrict__ Bt,
                                                  const float* __restrict__ bias,
                                                  void* Cv, int M, int K) {
    __shared__ __half As[2][128 * LSTR];
    __shared__ __half Bs[2][256 * LSTR];
    int tid = threadIdx.x;
    int wave = tid >> 6, lane = tid & 63;
    int wm = wave >> 2, wn = wave & 3;          // 2 x 4 wave grid
    int q = lane >> 4, m16 = lane & 15;
    int r0 = blockIdx.x * 128;

    // staging coordinates
    int ar  = tid >> 2, akq = (tid & 3) * 8;    // A: 128 rows x 32 k, 16 B/thread
    int br  = tid >> 1, bkq = (tid & 1) * 16;   // B: 256 rows x 32 k, 32 B/thread

    int arow = r0 + ar; if (arow >= M) arow = M - 1;

    f32x4 acc[4][4] = {};

    // prefetch registers (tile t+1)
    float4 afr0, afr1;      // A_F32 path
    uint4  areg;            // A fp16 path
    uint4  breg0, breg1;

    auto loadA = [&](int k0) {
        if (A_F32) {
            const float* src; int stride, kk0;
            if (k0 < KA) { src = (const float*)Av;  stride = strideA;  kk0 = k0; }
            else         { src = (const float*)A2v; stride = strideA2; kk0 = k0 - KA; }
            const float* p = &src[(size_t)arow * stride + kk0 + akq];
            afr0 = *reinterpret_cast<const float4*>(p);
            afr1 = *reinterpret_cast<const float4*>(p + 4);
        } else {
            const __half* src = (const __half*)Av;
            areg = *reinterpret_cast<const uint4*>(&src[(size_t)arow * strideA + k0 + akq]);
        }
    };
    auto loadB = [&](int k0) {
        const __half* p = &Bt[(size_t)br * K + k0 + bkq];
        breg0 = *reinterpret_cast<const uint4*>(p);
        breg1 = *reinterpret_cast<const uint4*>(p + 8);
    };
    auto writeLDS = [&](int buf) {
        if (A_F32) {
            union { __half2 h2[4]; uint4 u; } uu;
            uu.h2[0] = __floats2half2_rn(afr0.x, afr0.y);
            uu.h2[1] = __floats2half2_rn(afr0.z, afr0.w);
            uu.h2[2] = __floats2half2_rn(afr1.x, afr1.y);
            uu.h2[3] = __floats2half2_rn(afr1.z, afr1.w);
            *reinterpret_cast<uint4*>(&As[buf][ar * LSTR + akq]) = uu.u;
        } else {
            *reinterpret_cast<uint4*>(&As[buf][ar * LSTR + akq]) = areg;
        }
        *reinterpret_cast<uint4*>(&Bs[buf][br * LSTR + bkq])     = breg0;
        *reinterpret_cast<uint4*>(&Bs[buf][br * LSTR + bkq + 8]) = breg1;
    };

    const int S = K / KT;
    loadA(0); loadB(0);
    writeLDS(0);
    __syncthreads();

    for (int t = 0; t < S; ++t) {
        int cur = t & 1;
        if (t + 1 < S) { loadA((t + 1) * KT); loadB((t + 1) * KT); }  // hide under MFMA

        half8 af[4], bf[4];
        #pragma unroll
        for (int mi = 0; mi < 4; ++mi)
            af[mi] = *reinterpret_cast<const half8*>(&As[cur][(wm * 64 + mi * 16 + m16) * LSTR + q * 8]);
        #pragma unroll
        for (int ni = 0; ni < 4; ++ni)
            bf[ni] = *reinterpret_cast<const half8*>(&Bs[cur][(wn * 64 + ni * 16 + m16) * LSTR + q * 8]);
        #pragma unroll
        for (int mi = 0; mi < 4; ++mi)
            #pragma unroll
            for (int ni = 0; ni < 4; ++ni)
                acc[mi][ni] = __builtin_amdgcn_mfma_f32_16x16x32_f16(af[mi], bf[ni], acc[mi][ni], 0, 0, 0);

        if (t + 1 < S) writeLDS(cur ^ 1);   // waits vmcnt on prefetch regs, post-MFMA
        __syncthreads();                     // single barrier per K-step
    }

    // epilogue
    #pragma unroll
    for (int mi = 0; mi < 4; ++mi) {
        #pragma unroll
        for (int r = 0; r < 4; ++r) {
            int row = r0 + wm * 64 + mi * 16 + q * 4 + r;
            if (row >= M) continue;
            #pragma unroll
            for (int ni = 0; ni < 4; ++ni) {
                int col = wn * 64 + ni * 16 + m16;
                float v = acc[mi][ni][r];
                if (ADD_BIAS) v += bias[col];
                if (HALF_OUT) ((__half*)Cv)[(size_t)row * HID + col] = __float2half(v);
                else          ((float*)Cv)[(size_t)row * HID + col] = v;
            }
        }
    }
}

// ---------------------------------------------------------------------------
// Aggregation, wave-per-node, barrier-free (round-0 verified version):
// h[i,c] = relu( sum_e xh[src_e,c]*dis[src]*dis[i] + xh[i,c]*dis[i]^2 + b[c] )
// 256-thread block = 4 waves = 4 nodes. Lane owns 4 channels (one 8B load per
// edge). Edge idx/weight staged in registers, broadcast via __shfl. 4-edge
// unroll -> 4 independent 8B loads in flight per lane.
// NOTE (rounds 1-2 post-mortem): this runs at ~59 us = 218 MB of L2-miss
// traffic at ~3.7-4 TB/s, the effective ceiling for this random-line gather.
// NT hints (+15 MB fetch) and deeper unrolls (+write-back shift) only ADD
// bytes; dur tracks bytes/3.7TB/s in every variant. Do not touch the inner
// loop. Round-5: node range [i0,i1) so each layer's agg is split into two
// independent half dispatches (top-5 attribution instrument; same total work).
// ---------------------------------------------------------------------------
__global__ __launch_bounds__(256) void k_agg(const __half* __restrict__ xh,
                                             const int* __restrict__ rowptr,
                                             const int* __restrict__ csr,
                                             const float* __restrict__ dis,
                                             const float* __restrict__ bias,
                                             __half* __restrict__ outh, int i0, int i1) {
    int i = i0 + blockIdx.x * 4 + (threadIdx.x >> 6);
    if (i >= i1) return;
    int lane = threadIdx.x & 63;
    int c4 = lane * 4;
    float disd = dis[i];
    int e0 = rowptr[i], e1 = rowptr[i + 1];

    float acc0, acc1, acc2, acc3;
    {
        uint2 v = *reinterpret_cast<const uint2*>(&xh[(size_t)i * HID + c4]);
        float2 f0 = __half22float2(*reinterpret_cast<__half2*>(&v.x));
        float2 f1 = __half22float2(*reinterpret_cast<__half2*>(&v.y));
        float ws = disd * disd;
        acc0 = f0.x * ws; acc1 = f0.y * ws; acc2 = f1.x * ws; acc3 = f1.y * ws;
    }

    for (int e = e0; e < e1; e += 64) {
        int cnt = min(64, e1 - e);
        int sreg = 0; float wreg = 0.0f;
        if (lane < cnt) {
            sreg = csr[e + lane];
            wreg = dis[sreg] * disd;
        }
        int j = 0;
        for (; j + 4 <= cnt; j += 4) {
            int   s0 = __shfl(sreg, j + 0), s1 = __shfl(sreg, j + 1);
            int   s2 = __shfl(sreg, j + 2), s3 = __shfl(sreg, j + 3);
            float w0 = __shfl(wreg, j + 0), w1 = __shfl(wreg, j + 1);
            float w2 = __shfl(wreg, j + 2), w3 = __shfl(wreg, j + 3);
            uint2 v0 = *reinterpret_cast<const uint2*>(&xh[(size_t)s0 * HID + c4]);
            uint2 v1 = *reinterpret_cast<const uint2*>(&xh[(size_t)s1 * HID + c4]);
            uint2 v2 = *reinterpret_cast<const uint2*>(&xh[(size_t)s2 * HID + c4]);
            uint2 v3 = *reinterpret_cast<const uint2*>(&xh[(size_t)s3 * HID + c4]);
            float2 a0 = __half22float2(*reinterpret_cast<__half2*>(&v0.x));
            float2 b0 = __half22float2(*reinterpret_cast<__half2*>(&v0.y));
            float2 a1 = __half22float2(*reinterpret_cast<__half2*>(&v1.x));
            float2 b1 = __half22float2(*reinterpret_cast<__half2*>(&v1.y));
            float2 a2 = __half22float2(*reinterpret_cast<__half2*>(&v2.x));
            float2 b2 = __half22float2(*reinterpret_cast<__half2*>(&v2.y));
            float2 a3 = __half22float2(*reinterpret_cast<__half2*>(&v3.x));
            float2 b3 = __half22float2(*reinterpret_cast<__half2*>(&v3.y));
            acc0 = fmaf(a0.x, w0, acc0); acc1 = fmaf(a0.y, w0, acc1);
            acc2 = fmaf(b0.x, w0, acc2); acc3 = fmaf(b0.y, w0, acc3);
            acc0 = fmaf(a1.x, w1, acc0); acc1 = fmaf(a1.y, w1, acc1);
            acc2 = fmaf(b1.x, w1, acc2); acc3 = fmaf(b1.y, w1, acc3);
            acc0 = fmaf(a2.x, w2, acc0); acc1 = fmaf(a2.y, w2, acc1);
            acc2 = fmaf(b2.x, w2, acc2); acc3 = fmaf(b2.y, w2, acc3);
            acc0 = fmaf(a3.x, w3, acc0); acc1 = fmaf(a3.y, w3, acc1);
            acc2 = fmaf(b3.x, w3, acc2); acc3 = fmaf(b3.y, w3, acc3);
        }
        for (; j < cnt; ++j) {
            int   s = __shfl(sreg, j);
            float w = __shfl(wreg, j);
            uint2 v = *reinterpret_cast<const uint2*>(&xh[(size_t)s * HID + c4]);
            float2 a = __half22float2(*reinterpret_cast<__half2*>(&v.x));
            float2 b = __half22float2(*reinterpret_cast<__half2*>(&v.y));
            acc0 = fmaf(a.x, w, acc0); acc1 = fmaf(a.y, w, acc1);
            acc2 = fmaf(b.x, w, acc2); acc3 = fmaf(b.y, w, acc3);
        }
    }

    float4 bb = *reinterpret_cast<const float4*>(&bias[c4]);
    union { __half2 h2[2]; uint2 u; } o;
    o.h2[0] = __floats2half2_rn(fmaxf(acc0 + bb.x, 0.0f), fmaxf(acc1 + bb.y, 0.0f));
    o.h2[1] = __floats2half2_rn(fmaxf(acc2 + bb.z, 0.0f), fmaxf(acc3 + bb.w, 0.0f));
    *reinterpret_cast<uint2*>(&outh[(size_t)i * HID + c4]) = o.u;
}

// ---------------------------------------------------------------------------
extern "C" void kernel_launch(void* const* d_in, const int* in_sizes, int n_in,
                              void* d_out, int out_size, void* d_ws, size_t ws_size,
                              hipStream_t stream) {
    const float* x     = (const float*)d_in[0];
    const float* rni   = (const float*)d_in[1];
    const unsigned int* ew = (const unsigned int*)d_in[2];
    const float* W1    = (const float*)d_in[3];
    const float* b1    = (const float*)d_in[4];
    const float* W2    = (const float*)d_in[5];
    const float* b2    = (const float*)d_in[6];
    const float* W_out = (const float*)d_in[7];
    const float* b_out = (const float*)d_in[8];
    float* out = (float*)d_out;

    const int n  = in_sizes[0] / D_IN;     // 50000
    const int e  = in_sizes[2] / 2;        // 800000
    const int nb = (n + 1023) / 1024;
    const int K1 = D_IN + D_RNI;           // 160

    char* ws = (char*)d_ws;
    size_t off = 0;
    auto carve = [&](size_t bytes) {
        char* p = ws + off;
        off = (off + bytes + 255) & ~(size_t)255;
        return p;
    };
    __half* xh    = (__half*)carve((size_t)n * HID * sizeof(__half));   // 25.6 MB
    __half* h     = (__half*)carve((size_t)n * HID * sizeof(__half));   // 25.6 MB
    __half* W1t   = (__half*)carve((size_t)K1 * HID * sizeof(__half));
    __half* W2t   = (__half*)carve((size_t)HID * HID * sizeof(__half));
    __half* Wot   = (__half*)carve((size_t)HID * HID * sizeof(__half));
    int*   counts = (int*)carve((size_t)n * sizeof(int));
    int*   incl   = (int*)carve((size_t)n * sizeof(int));
    int*   bsum   = (int*)carve((size_t)(nb + 1) * sizeof(int));
    int*   rowptr = (int*)carve((size_t)(n + 1) * sizeof(int));
    int*   cursor = (int*)carve((size_t)n * sizeof(int));
    float* dis    = (float*)carve((size_t)n * sizeof(float));
    int*   csr    = (int*)carve((size_t)e * sizeof(int));
    int*   mode   = (int*)carve(sizeof(int));
    (void)ws_size;

    const int eb = (e + 255) / 256;
    const int gemm_blocks = (n + 127) / 128;
    const int TW = K1 * HID + 2 * HID * HID;                      // weight elements
    const int prep_blocks = 1 + (TW + n + 255) / 256;             // detect + cvt + zero

    // node split point for the two agg half-dispatches (multiple of 4)
    const int half = ((n + 7) / 8) * 4;
    const int aggb1 = (half + 3) / 4;
    const int aggb2 = (n - half + 3) / 4;

    // --- prep (detect + weight cvt + counts=0) and CSR build
    k_prep<<<prep_blocks, 256, 0, stream>>>(ew, 2 * e, mode, W1, W1t, W2, W2t, W_out, Wot,
                                            counts, n);
    k_count<<<eb, 256, 0, stream>>>(ew, mode, counts, e);
    k_scan1<<<nb, 1024, 0, stream>>>(counts, incl, bsum, n);
    k_scan3<<<(n + 255) / 256, 256, 0, stream>>>(counts, incl, bsum, rowptr, cursor, dis, n, nb);
    k_scatter<<<eb, 256, 0, stream>>>(ew, mode, cursor, csr, e);

    // --- layer 1 (fp32 inputs converted in GEMM staging)
    k_mgemm<true, false, true><<<gemm_blocks, 512, 0, stream>>>(x, D_IN, D_IN, rni, D_RNI,
                                                                W1t, nullptr, xh, n, K1);
    k_agg<<<aggb1, 256, 0, stream>>>(xh, rowptr, csr, dis, b1, h, 0, half);
    k_agg<<<aggb2, 256, 0, stream>>>(xh, rowptr, csr, dis, b1, h, half, n);

    // --- layer 2
    k_mgemm<false, false, true><<<gemm_blocks, 512, 0, stream>>>(h, HID, HID, nullptr, 0,
                                                                 W2t, nullptr, xh, n, HID);
    k_agg<<<aggb1, 256, 0, stream>>>(xh, rowptr, csr, dis, b2, h, 0, half);
    k_agg<<<aggb2, 256, 0, stream>>>(xh, rowptr, csr, dis, b2, h, half, n);

    // --- output layer (fp32 out + bias)
    k_mgemm<false, true, false><<<gemm_blocks, 512, 0, stream>>>(h, HID, HID, nullptr, 0,
                                                                 Wot, b_out, out, n, HID);
}

// Round 7
// 360.624 us; speedup vs baseline: 1.0264x; 1.0264x over previous
//
#include <hip/hip_runtime.h>
#include <hip/hip_bf16.h>
#include <hip/hip_fp16.h>
#include <math.h>

#define D_IN   128
#define D_RNI  32
#define HID    256

typedef _Float16 half8 __attribute__((ext_vector_type(8)));
typedef float    f32x4 __attribute__((ext_vector_type(4)));

// ---------------------------------------------------------------------------
// k_prep: fused {edge dtype detect} + {3x weight transpose/cast} + {counts=0}.
// ---------------------------------------------------------------------------
__global__ void k_prep(const unsigned int* __restrict__ ew, int nwords, int* __restrict__ mode,
                       const float* __restrict__ W1, __half* __restrict__ W1t,
                       const float* __restrict__ W2, __half* __restrict__ W2t,
                       const float* __restrict__ Wo, __half* __restrict__ Wot,
                       int* __restrict__ counts, int n) {
    int b = blockIdx.x;
    if (b == 0) {
        __shared__ unsigned int red[256];
        unsigned int acc = 0;
        for (int i = threadIdx.x; i < 1024; i += 256) {
            int idx = 2 * i + 1;
            if (idx < nwords) acc |= ew[idx];
        }
        red[threadIdx.x] = acc;
        __syncthreads();
        for (int s = 128; s > 0; s >>= 1) {
            if (threadIdx.x < s) red[threadIdx.x] |= red[threadIdx.x + s];
            __syncthreads();
        }
        if (threadIdx.x == 0) *mode = (red[0] == 0u) ? 1 : 0;
        return;
    }
    const int T1 = (D_IN + D_RNI) * HID;   // 40960  (160 blocks)
    const int T2 = HID * HID;              // 65536  (256 blocks each)
    const int TW = T1 + 2 * T2;            // 172032 (672 blocks)
    int i = (b - 1) * 256 + threadIdx.x;
    if (i < T1) {
        int k = i / HID, nn = i - k * HID;
        W1t[(size_t)nn * (D_IN + D_RNI) + k] = __float2half(W1[i]);
    } else if (i < T1 + T2) {
        int j = i - T1;
        int k = j / HID, nn = j - k * HID;
        W2t[(size_t)nn * HID + k] = __float2half(W2[j]);
    } else if (i < TW) {
        int j = i - T1 - T2;
        int k = j / HID, nn = j - k * HID;
        Wot[(size_t)nn * HID + k] = __float2half(Wo[j]);
    } else {
        int j = i - TW;
        if (j < n) counts[j] = 0;
    }
}

__global__ void k_count(const unsigned int* __restrict__ ew, const int* __restrict__ mode_p,
                        int* __restrict__ counts, int e) {
    int mode = *mode_p;
    int i = blockIdx.x * 256 + threadIdx.x;
    if (i >= e) return;
    int d = mode ? (int)ew[2 * ((size_t)e + i)] : (int)ew[(size_t)e + i];
    atomicAdd(&counts[d], 1);
}

// ---------------------------------------------------------------------------
// Scan: k_scan1 per-1024-chunk inclusive scans + chunk sums; k_scan3 folds the
// (<=64-entry) chunk-sum prefix via a wave reduce.
// ---------------------------------------------------------------------------
__global__ __launch_bounds__(1024) void k_scan1(const int* __restrict__ counts,
                                                int* __restrict__ incl,
                                                int* __restrict__ bsum, int n) {
    __shared__ int sd[1024];
    int t = threadIdx.x;
    int i = blockIdx.x * 1024 + t;
    int v = (i < n) ? counts[i] : 0;
    sd[t] = v;
    __syncthreads();
    for (int off = 1; off < 1024; off <<= 1) {
        int tmp = (t >= off) ? sd[t - off] : 0;
        __syncthreads();
        sd[t] += tmp;
        __syncthreads();
    }
    if (i < n) incl[i] = sd[t];
    if (t == 1023) bsum[blockIdx.x] = sd[1023];
}

__global__ void k_scan3(const int* __restrict__ counts, const int* __restrict__ incl,
                        const int* __restrict__ bsum,
                        int* __restrict__ rowptr, int* __restrict__ cursor,
                        float* __restrict__ dis, int n, int nb) {
    __shared__ int pre_s, tot_s;
    int t = threadIdx.x;
    int c = (blockIdx.x * 256) >> 10;
    if (t < 64) {
        int v   = (t < nb) ? bsum[t] : 0;
        int pre = (t < c)  ? v : 0;
        int tot = v;
        #pragma unroll
        for (int m = 32; m > 0; m >>= 1) {
            pre += __shfl_down(pre, m);
            tot += __shfl_down(tot, m);
        }
        if (t == 0) { pre_s = pre; tot_s = tot; }
    }
    __syncthreads();
    int i = blockIdx.x * 256 + t;
    if (i >= n) return;
    int excl = incl[i] - counts[i] + pre_s;
    rowptr[i] = excl;
    cursor[i] = excl;
    dis[i] = 1.0f / sqrtf((float)(counts[i] + 1));
    if (i == 0) rowptr[n] = tot_s;
}

// ---------------------------------------------------------------------------
// GEMM body (device fn): C[M x 256] = A[M x K] @ Bt^T  (Bt:[N=256][K] fp16).
// 512 threads = 8 waves as 2(M)x4(N); tile 128 M x 256 N. LDS double-buffer,
// one barrier per K-step; prefetch loads hidden under MFMA. LSTR=40 padding,
// verified fragment layout. Shared by k_mgemm and the fused k_scatgemm.
// ---------------------------------------------------------------------------
#define KT 32
#define LSTR 40
template <bool A_F32, bool ADD_BIAS, bool HALF_OUT>
__device__ __forceinline__ void gemm_body(int blk,
                                          const void* __restrict__ Av, int strideA, int KA,
                                          const void* __restrict__ A2v, int strideA2,
                                          const __half* __restrict__ Bt,
                                          const float* __restrict__ bias,
                                          void* Cv, int M, int K) {
    __shared__ __half As[2][128 * LSTR];
    __shared__ __half Bs[2][256 * LSTR];
    int tid = threadIdx.x;
    int wave = tid >> 6, lane = tid & 63;
    int wm = wave >> 2, wn = wave & 3;          // 2 x 4 wave grid
    int q = lane >> 4, m16 = lane & 15;
    int r0 = blk * 128;

    int ar  = tid >> 2, akq = (tid & 3) * 8;    // A: 128 rows x 32 k
    int br  = tid >> 1, bkq = (tid & 1) * 16;   // B: 256 rows x 32 k

    int arow = r0 + ar; if (arow >= M) arow = M - 1;

    f32x4 acc[4][4] = {};

    float4 afr0, afr1;
    uint4  areg;
    uint4  breg0, breg1;

    auto loadA = [&](int k0) {
        if (A_F32) {
            const float* src; int stride, kk0;
            if (k0 < KA) { src = (const float*)Av;  stride = strideA;  kk0 = k0; }
            else         { src = (const float*)A2v; stride = strideA2; kk0 = k0 - KA; }
            const float* p = &src[(size_t)arow * stride + kk0 + akq];
            afr0 = *reinterpret_cast<const float4*>(p);
            afr1 = *reinterpret_cast<const float4*>(p + 4);
        } else {
            const __half* src = (const __half*)Av;
            areg = *reinterpret_cast<const uint4*>(&src[(size_t)arow * strideA + k0 + akq]);
        }
    };
    auto loadB = [&](int k0) {
        const __half* p = &Bt[(size_t)br * K + k0 + bkq];
        breg0 = *reinterpret_cast<const uint4*>(p);
        breg1 = *reinterpret_cast<const uint4*>(p + 8);
    };
    auto writeLDS = [&](int buf) {
        if (A_F32) {
            union { __half2 h2[4]; uint4 u; } uu;
            uu.h2[0] = __floats2half2_rn(afr0.x, afr0.y);
            uu.h2[1] = __floats2half2_rn(afr0.z, afr0.w);
            uu.h2[2] = __floats2half2_rn(afr1.x, afr1.y);
            uu.h2[3] = __floats2half2_rn(afr1.z, afr1.w);
            *reinterpret_cast<uint4*>(&As[buf][ar * LSTR + akq]) = uu.u;
        } else {
            *reinterpret_cast<uint4*>(&As[buf][ar * LSTR + akq]) = areg;
        }
        *reinterpret_cast<uint4*>(&Bs[buf][br * LSTR + bkq])     = breg0;
        *reinterpret_cast<uint4*>(&Bs[buf][br * LSTR + bkq + 8]) = breg1;
    };

    const int S = K / KT;
    loadA(0); loadB(0);
    writeLDS(0);
    __syncthreads();

    for (int t = 0; t < S; ++t) {
        int cur = t & 1;
        if (t + 1 < S) { loadA((t + 1) * KT); loadB((t + 1) * KT); }

        half8 af[4], bf[4];
        #pragma unroll
        for (int mi = 0; mi < 4; ++mi)
            af[mi] = *reinterpret_cast<const half8*>(&As[cur][(wm * 64 + mi * 16 + m16) * LSTR + q * 8]);
        #pragma unroll
        for (int ni = 0; ni < 4; ++ni)
            bf[ni] = *reinterpret_cast<const half8*>(&Bs[cur][(wn * 64 + ni * 16 + m16) * LSTR + q * 8]);
        #pragma unroll
        for (int mi = 0; mi < 4; ++mi)
            #pragma unroll
            for (int ni = 0; ni < 4; ++ni)
                acc[mi][ni] = __builtin_amdgcn_mfma_f32_16x16x32_f16(af[mi], bf[ni], acc[mi][ni], 0, 0, 0);

        if (t + 1 < S) writeLDS(cur ^ 1);
        __syncthreads();
    }

    #pragma unroll
    for (int mi = 0; mi < 4; ++mi) {
        #pragma unroll
        for (int r = 0; r < 4; ++r) {
            int row = r0 + wm * 64 + mi * 16 + q * 4 + r;
            if (row >= M) continue;
            #pragma unroll
            for (int ni = 0; ni < 4; ++ni) {
                int col = wn * 64 + ni * 16 + m16;
                float v = acc[mi][ni][r];
                if (ADD_BIAS) v += bias[col];
                if (HALF_OUT) ((__half*)Cv)[(size_t)row * HID + col] = __float2half(v);
                else          ((float*)Cv)[(size_t)row * HID + col] = v;
            }
        }
    }
}

template <bool A_F32, bool ADD_BIAS, bool HALF_OUT>
__global__ __launch_bounds__(512, 4) void k_mgemm(const void* __restrict__ Av, int strideA, int KA,
                                                  const void* __restrict__ A2v, int strideA2,
                                                  const __half* __restrict__ Bt,
                                                  const float* __restrict__ bias,
                                                  void* Cv, int M, int K) {
    gemm_body<A_F32, ADD_BIAS, HALF_OUT>(blockIdx.x, Av, strideA, KA, A2v, strideA2,
                                         Bt, bias, Cv, M, K);
}

// ---------------------------------------------------------------------------
// Fused scatter + layer-1 GEMM.
// Round-5 counters: k_scatter = 54 us, VALUBusy 0.35%, 13% HBM, WRITE 52.9 MB
// (= 800k edges x 64 B: every random 4B csr store dirties a 64B sector across
// non-coherent XCD L2s -> 16x write amplification at the ~1 TB/s scattered-
// sector ceiling). It uses no MFMA and little VALU/BW -> overlap it with the
// independent layer-1 GEMM in ONE dispatch: blocks [0,GB) = GEMM, rest =
// scatter (512-thr, 1 edge/thread). Disjoint resources -> GEMM rides free.
// Branch is uniform per block (on blockIdx), so gemm_body's barriers are safe.
// ---------------------------------------------------------------------------
__global__ __launch_bounds__(512, 4) void k_scatgemm(
        const unsigned int* __restrict__ ew, const int* __restrict__ mode_p,
        int* __restrict__ cursor, int* __restrict__ csr, int e, int gemm_blocks,
        const float* __restrict__ x, const float* __restrict__ rni,
        const __half* __restrict__ W1t, __half* __restrict__ xh, int M, int K) {
    if ((int)blockIdx.x < gemm_blocks) {
        gemm_body<true, false, true>(blockIdx.x, x, D_IN, D_IN, rni, D_RNI,
                                     W1t, nullptr, xh, M, K);
        return;
    }
    int i = ((int)blockIdx.x - gemm_blocks) * 512 + (int)threadIdx.x;
    if (i >= e) return;
    int mode = *mode_p;
    int s, d;
    if (mode) {
        s = (int)ew[2 * (size_t)i];
        d = (int)ew[2 * ((size_t)e + i)];
    } else {
        s = (int)ew[(size_t)i];
        d = (int)ew[(size_t)e + i];
    }
    int pos = atomicAdd(&cursor[d], 1);
    csr[pos] = s;
}

// ---------------------------------------------------------------------------
// Aggregation, wave-per-node, barrier-free (round-0 verified version):
// h[i,c] = relu( sum_e xh[src_e,c]*dis[src]*dis[i] + xh[i,c]*dis[i]^2 + b[c] )
// ~59 us = 218 MB of L2-miss traffic at ~3.7-4 TB/s, the effective ceiling for
// this random-line gather. Rounds 1-2: NT hints / deeper unrolls only ADD
// bytes; dur tracks bytes/3.7TB/s in every variant. Do not touch.
// ---------------------------------------------------------------------------
__global__ __launch_bounds__(256) void k_agg(const __half* __restrict__ xh,
                                             const int* __restrict__ rowptr,
                                             const int* __restrict__ csr,
                                             const float* __restrict__ dis,
                                             const float* __restrict__ bias,
                                             __half* __restrict__ outh, int n) {
    int i = blockIdx.x * 4 + (threadIdx.x >> 6);
    if (i >= n) return;
    int lane = threadIdx.x & 63;
    int c4 = lane * 4;
    float disd = dis[i];
    int e0 = rowptr[i], e1 = rowptr[i + 1];

    float acc0, acc1, acc2, acc3;
    {
        uint2 v = *reinterpret_cast<const uint2*>(&xh[(size_t)i * HID + c4]);
        float2 f0 = __half22float2(*reinterpret_cast<__half2*>(&v.x));
        float2 f1 = __half22float2(*reinterpret_cast<__half2*>(&v.y));
        float ws = disd * disd;
        acc0 = f0.x * ws; acc1 = f0.y * ws; acc2 = f1.x * ws; acc3 = f1.y * ws;
    }

    for (int e = e0; e < e1; e += 64) {
        int cnt = min(64, e1 - e);
        int sreg = 0; float wreg = 0.0f;
        if (lane < cnt) {
            sreg = csr[e + lane];
            wreg = dis[sreg] * disd;
        }
        int j = 0;
        for (; j + 4 <= cnt; j += 4) {
            int   s0 = __shfl(sreg, j + 0), s1 = __shfl(sreg, j + 1);
            int   s2 = __shfl(sreg, j + 2), s3 = __shfl(sreg, j + 3);
            float w0 = __shfl(wreg, j + 0), w1 = __shfl(wreg, j + 1);
            float w2 = __shfl(wreg, j + 2), w3 = __shfl(wreg, j + 3);
            uint2 v0 = *reinterpret_cast<const uint2*>(&xh[(size_t)s0 * HID + c4]);
            uint2 v1 = *reinterpret_cast<const uint2*>(&xh[(size_t)s1 * HID + c4]);
            uint2 v2 = *reinterpret_cast<const uint2*>(&xh[(size_t)s2 * HID + c4]);
            uint2 v3 = *reinterpret_cast<const uint2*>(&xh[(size_t)s3 * HID + c4]);
            float2 a0 = __half22float2(*reinterpret_cast<__half2*>(&v0.x));
            float2 b0 = __half22float2(*reinterpret_cast<__half2*>(&v0.y));
            float2 a1 = __half22float2(*reinterpret_cast<__half2*>(&v1.x));
            float2 b1 = __half22float2(*reinterpret_cast<__half2*>(&v1.y));
            float2 a2 = __half22float2(*reinterpret_cast<__half2*>(&v2.x));
            float2 b2 = __half22float2(*reinterpret_cast<__half2*>(&v2.y));
            float2 a3 = __half22float2(*reinterpret_cast<__half2*>(&v3.x));
            float2 b3 = __half22float2(*reinterpret_cast<__half2*>(&v3.y));
            acc0 = fmaf(a0.x, w0, acc0); acc1 = fmaf(a0.y, w0, acc1);
            acc2 = fmaf(b0.x, w0, acc2); acc3 = fmaf(b0.y, w0, acc3);
            acc0 = fmaf(a1.x, w1, acc0); acc1 = fmaf(a1.y, w1, acc1);
            acc2 = fmaf(b1.x, w1, acc2); acc3 = fmaf(b1.y, w1, acc3);
            acc0 = fmaf(a2.x, w2, acc0); acc1 = fmaf(a2.y, w2, acc1);
            acc2 = fmaf(b2.x, w2, acc2); acc3 = fmaf(b2.y, w2, acc3);
            acc0 = fmaf(a3.x, w3, acc0); acc1 = fmaf(a3.y, w3, acc1);
            acc2 = fmaf(b3.x, w3, acc2); acc3 = fmaf(b3.y, w3, acc3);
        }
        for (; j < cnt; ++j) {
            int   s = __shfl(sreg, j);
            float w = __shfl(wreg, j);
            uint2 v = *reinterpret_cast<const uint2*>(&xh[(size_t)s * HID + c4]);
            float2 a = __half22float2(*reinterpret_cast<__half2*>(&v.x));
            float2 b = __half22float2(*reinterpret_cast<__half2*>(&v.y));
            acc0 = fmaf(a.x, w, acc0); acc1 = fmaf(a.y, w, acc1);
            acc2 = fmaf(b.x, w, acc2); acc3 = fmaf(b.y, w, acc3);
        }
    }

    float4 bb = *reinterpret_cast<const float4*>(&bias[c4]);
    union { __half2 h2[2]; uint2 u; } o;
    o.h2[0] = __floats2half2_rn(fmaxf(acc0 + bb.x, 0.0f), fmaxf(acc1 + bb.y, 0.0f));
    o.h2[1] = __floats2half2_rn(fmaxf(acc2 + bb.z, 0.0f), fmaxf(acc3 + bb.w, 0.0f));
    *reinterpret_cast<uint2*>(&outh[(size_t)i * HID + c4]) = o.u;
}

// ---------------------------------------------------------------------------
extern "C" void kernel_launch(void* const* d_in, const int* in_sizes, int n_in,
                              void* d_out, int out_size, void* d_ws, size_t ws_size,
                              hipStream_t stream) {
    const float* x     = (const float*)d_in[0];
    const float* rni   = (const float*)d_in[1];
    const unsigned int* ew = (const unsigned int*)d_in[2];
    const float* W1    = (const float*)d_in[3];
    const float* b1    = (const float*)d_in[4];
    const float* W2    = (const float*)d_in[5];
    const float* b2    = (const float*)d_in[6];
    const float* W_out = (const float*)d_in[7];
    const float* b_out = (const float*)d_in[8];
    float* out = (float*)d_out;

    const int n  = in_sizes[0] / D_IN;     // 50000
    const int e  = in_sizes[2] / 2;        // 800000
    const int nb = (n + 1023) / 1024;
    const int K1 = D_IN + D_RNI;           // 160

    char* ws = (char*)d_ws;
    size_t off = 0;
    auto carve = [&](size_t bytes) {
        char* p = ws + off;
        off = (off + bytes + 255) & ~(size_t)255;
        return p;
    };
    __half* xh    = (__half*)carve((size_t)n * HID * sizeof(__half));   // 25.6 MB
    __half* h     = (__half*)carve((size_t)n * HID * sizeof(__half));   // 25.6 MB
    __half* W1t   = (__half*)carve((size_t)K1 * HID * sizeof(__half));
    __half* W2t   = (__half*)carve((size_t)HID * HID * sizeof(__half));
    __half* Wot   = (__half*)carve((size_t)HID * HID * sizeof(__half));
    int*   counts = (int*)carve((size_t)n * sizeof(int));
    int*   incl   = (int*)carve((size_t)n * sizeof(int));
    int*   bsum   = (int*)carve((size_t)(nb + 1) * sizeof(int));
    int*   rowptr = (int*)carve((size_t)(n + 1) * sizeof(int));
    int*   cursor = (int*)carve((size_t)n * sizeof(int));
    float* dis    = (float*)carve((size_t)n * sizeof(float));
    int*   csr    = (int*)carve((size_t)e * sizeof(int));
    int*   mode   = (int*)carve(sizeof(int));
    (void)ws_size;

    const int eb = (e + 255) / 256;
    const int gemm_blocks = (n + 127) / 128;
    const int agg_blocks  = (n + 3) / 4;
    const int TW = K1 * HID + 2 * HID * HID;
    const int prep_blocks = 1 + (TW + n + 255) / 256;

    // --- prep (detect + weight cvt + counts=0) and CSR chain
    k_prep<<<prep_blocks, 256, 0, stream>>>(ew, 2 * e, mode, W1, W1t, W2, W2t, W_out, Wot,
                                            counts, n);
    k_count<<<eb, 256, 0, stream>>>(ew, mode, counts, e);
    k_scan1<<<nb, 1024, 0, stream>>>(counts, incl, bsum, n);
    k_scan3<<<(n + 255) / 256, 256, 0, stream>>>(counts, incl, bsum, rowptr, cursor, dis, n, nb);

    // --- fused: edge scatter + layer-1 GEMM (independent of CSR chain)
    {
        const int sb = (e + 511) / 512;
        k_scatgemm<<<gemm_blocks + sb, 512, 0, stream>>>(ew, mode, cursor, csr, e, gemm_blocks,
                                                         x, rni, W1t, xh, n, K1);
    }
    k_agg<<<agg_blocks, 256, 0, stream>>>(xh, rowptr, csr, dis, b1, h, n);

    // --- layer 2
    k_mgemm<false, false, true><<<gemm_blocks, 512, 0, stream>>>(h, HID, HID, nullptr, 0,
                                                                 W2t, nullptr, xh, n, HID);
    k_agg<<<agg_blocks, 256, 0, stream>>>(xh, rowptr, csr, dis, b2, h, n);

    // --- output layer (fp32 out + bias)
    k_mgemm<false, true, false><<<gemm_blocks, 512, 0, stream>>>(h, HID, HID, nullptr, 0,
                                                                 Wot, b_out, out, n, HID);
}

// Round 8
// 343.682 us; speedup vs baseline: 1.0770x; 1.0493x over previous
//
#include <hip/hip_runtime.h>
#include <hip/hip_bf16.h>
#include <hip/hip_fp16.h>
#include <math.h>

#define D_IN   128
#define D_RNI  32
#define HID    256

typedef _Float16 half8 __attribute__((ext_vector_type(8)));
typedef float    f32x4 __attribute__((ext_vector_type(4)));

// ---------------------------------------------------------------------------
// k_prep: fused {edge dtype detect} + {3x weight transpose/cast} + {counts=0}.
// ---------------------------------------------------------------------------
__global__ void k_prep(const unsigned int* __restrict__ ew, int nwords, int* __restrict__ mode,
                       const float* __restrict__ W1, __half* __restrict__ W1t,
                       const float* __restrict__ W2, __half* __restrict__ W2t,
                       const float* __restrict__ Wo, __half* __restrict__ Wot,
                       int* __restrict__ counts, int n) {
    int b = blockIdx.x;
    if (b == 0) {
        __shared__ unsigned int red[256];
        unsigned int acc = 0;
        for (int i = threadIdx.x; i < 1024; i += 256) {
            int idx = 2 * i + 1;
            if (idx < nwords) acc |= ew[idx];
        }
        red[threadIdx.x] = acc;
        __syncthreads();
        for (int s = 128; s > 0; s >>= 1) {
            if (threadIdx.x < s) red[threadIdx.x] |= red[threadIdx.x + s];
            __syncthreads();
        }
        if (threadIdx.x == 0) *mode = (red[0] == 0u) ? 1 : 0;
        return;
    }
    const int T1 = (D_IN + D_RNI) * HID;   // 40960  (160 blocks)
    const int T2 = HID * HID;              // 65536  (256 blocks each)
    const int TW = T1 + 2 * T2;            // 172032 (672 blocks)
    int i = (b - 1) * 256 + threadIdx.x;
    if (i < T1) {
        int k = i / HID, nn = i - k * HID;
        W1t[(size_t)nn * (D_IN + D_RNI) + k] = __float2half(W1[i]);
    } else if (i < T1 + T2) {
        int j = i - T1;
        int k = j / HID, nn = j - k * HID;
        W2t[(size_t)nn * HID + k] = __float2half(W2[j]);
    } else if (i < TW) {
        int j = i - T1 - T2;
        int k = j / HID, nn = j - k * HID;
        Wot[(size_t)nn * HID + k] = __float2half(Wo[j]);
    } else {
        int j = i - TW;
        if (j < n) counts[j] = 0;
    }
}

__global__ void k_count(const unsigned int* __restrict__ ew, const int* __restrict__ mode_p,
                        int* __restrict__ counts, int e) {
    int mode = *mode_p;
    int i = blockIdx.x * 256 + threadIdx.x;
    if (i >= e) return;
    int d = mode ? (int)ew[2 * ((size_t)e + i)] : (int)ew[(size_t)e + i];
    atomicAdd(&counts[d], 1);
}

// ---------------------------------------------------------------------------
// Scan: k_scan1 per-1024-chunk inclusive scans + chunk sums; k_scan3 folds the
// (<=64-entry) chunk-sum prefix via a wave reduce.
// ---------------------------------------------------------------------------
__global__ __launch_bounds__(1024) void k_scan1(const int* __restrict__ counts,
                                                int* __restrict__ incl,
                                                int* __restrict__ bsum, int n) {
    __shared__ int sd[1024];
    int t = threadIdx.x;
    int i = blockIdx.x * 1024 + t;
    int v = (i < n) ? counts[i] : 0;
    sd[t] = v;
    __syncthreads();
    for (int off = 1; off < 1024; off <<= 1) {
        int tmp = (t >= off) ? sd[t - off] : 0;
        __syncthreads();
        sd[t] += tmp;
        __syncthreads();
    }
    if (i < n) incl[i] = sd[t];
    if (t == 1023) bsum[blockIdx.x] = sd[1023];
}

__global__ void k_scan3(const int* __restrict__ counts, const int* __restrict__ incl,
                        const int* __restrict__ bsum,
                        int* __restrict__ rowptr, int* __restrict__ cursor,
                        float* __restrict__ dis, int n, int nb) {
    __shared__ int pre_s, tot_s;
    int t = threadIdx.x;
    int c = (blockIdx.x * 256) >> 10;
    if (t < 64) {
        int v   = (t < nb) ? bsum[t] : 0;
        int pre = (t < c)  ? v : 0;
        int tot = v;
        #pragma unroll
        for (int m = 32; m > 0; m >>= 1) {
            pre += __shfl_down(pre, m);
            tot += __shfl_down(tot, m);
        }
        if (t == 0) { pre_s = pre; tot_s = tot; }
    }
    __syncthreads();
    int i = blockIdx.x * 256 + t;
    if (i >= n) return;
    int excl = incl[i] - counts[i] + pre_s;
    rowptr[i] = excl;
    cursor[i] = excl;
    dis[i] = 1.0f / sqrtf((float)(counts[i] + 1));
    if (i == 0) rowptr[n] = tot_s;
}

// ---------------------------------------------------------------------------
// GEMM body (device fn): C[M x 256] = A[M x K] @ Bt^T  (Bt:[N=256][K] fp16).
// 512 threads = 8 waves as 2(M)x4(N); tile 128 M x 256 N. LDS double-buffer,
// one barrier per K-step; prefetch loads hidden under MFMA. LSTR=40 padding,
// verified fragment layout. Shared by k_mgemm and the fused k_scatgemm.
// ---------------------------------------------------------------------------
#define KT 32
#define LSTR 40
template <bool A_F32, bool ADD_BIAS, bool HALF_OUT>
__device__ __forceinline__ void gemm_body(int blk,
                                          const void* __restrict__ Av, int strideA, int KA,
                                          const void* __restrict__ A2v, int strideA2,
                                          const __half* __restrict__ Bt,
                                          const float* __restrict__ bias,
                                          void* Cv, int M, int K) {
    __shared__ __half As[2][128 * LSTR];
    __shared__ __half Bs[2][256 * LSTR];
    int tid = threadIdx.x;
    int wave = tid >> 6, lane = tid & 63;
    int wm = wave >> 2, wn = wave & 3;          // 2 x 4 wave grid
    int q = lane >> 4, m16 = lane & 15;
    int r0 = blk * 128;

    int ar  = tid >> 2, akq = (tid & 3) * 8;    // A: 128 rows x 32 k
    int br  = tid >> 1, bkq = (tid & 1) * 16;   // B: 256 rows x 32 k

    int arow = r0 + ar; if (arow >= M) arow = M - 1;

    f32x4 acc[4][4] = {};

    float4 afr0, afr1;
    uint4  areg;
    uint4  breg0, breg1;

    auto loadA = [&](int k0) {
        if (A_F32) {
            const float* src; int stride, kk0;
            if (k0 < KA) { src = (const float*)Av;  stride = strideA;  kk0 = k0; }
            else         { src = (const float*)A2v; stride = strideA2; kk0 = k0 - KA; }
            const float* p = &src[(size_t)arow * stride + kk0 + akq];
            afr0 = *reinterpret_cast<const float4*>(p);
            afr1 = *reinterpret_cast<const float4*>(p + 4);
        } else {
            const __half* src = (const __half*)Av;
            areg = *reinterpret_cast<const uint4*>(&src[(size_t)arow * strideA + k0 + akq]);
        }
    };
    auto loadB = [&](int k0) {
        const __half* p = &Bt[(size_t)br * K + k0 + bkq];
        breg0 = *reinterpret_cast<const uint4*>(p);
        breg1 = *reinterpret_cast<const uint4*>(p + 8);
    };
    auto writeLDS = [&](int buf) {
        if (A_F32) {
            union { __half2 h2[4]; uint4 u; } uu;
            uu.h2[0] = __floats2half2_rn(afr0.x, afr0.y);
            uu.h2[1] = __floats2half2_rn(afr0.z, afr0.w);
            uu.h2[2] = __floats2half2_rn(afr1.x, afr1.y);
            uu.h2[3] = __floats2half2_rn(afr1.z, afr1.w);
            *reinterpret_cast<uint4*>(&As[buf][ar * LSTR + akq]) = uu.u;
        } else {
            *reinterpret_cast<uint4*>(&As[buf][ar * LSTR + akq]) = areg;
        }
        *reinterpret_cast<uint4*>(&Bs[buf][br * LSTR + bkq])     = breg0;
        *reinterpret_cast<uint4*>(&Bs[buf][br * LSTR + bkq + 8]) = breg1;
    };

    const int S = K / KT;
    loadA(0); loadB(0);
    writeLDS(0);
    __syncthreads();

    for (int t = 0; t < S; ++t) {
        int cur = t & 1;
        if (t + 1 < S) { loadA((t + 1) * KT); loadB((t + 1) * KT); }

        half8 af[4], bf[4];
        #pragma unroll
        for (int mi = 0; mi < 4; ++mi)
            af[mi] = *reinterpret_cast<const half8*>(&As[cur][(wm * 64 + mi * 16 + m16) * LSTR + q * 8]);
        #pragma unroll
        for (int ni = 0; ni < 4; ++ni)
            bf[ni] = *reinterpret_cast<const half8*>(&Bs[cur][(wn * 64 + ni * 16 + m16) * LSTR + q * 8]);
        #pragma unroll
        for (int mi = 0; mi < 4; ++mi)
            #pragma unroll
            for (int ni = 0; ni < 4; ++ni)
                acc[mi][ni] = __builtin_amdgcn_mfma_f32_16x16x32_f16(af[mi], bf[ni], acc[mi][ni], 0, 0, 0);

        if (t + 1 < S) writeLDS(cur ^ 1);
        __syncthreads();
    }

    #pragma unroll
    for (int mi = 0; mi < 4; ++mi) {
        #pragma unroll
        for (int r = 0; r < 4; ++r) {
            int row = r0 + wm * 64 + mi * 16 + q * 4 + r;
            if (row >= M) continue;
            #pragma unroll
            for (int ni = 0; ni < 4; ++ni) {
                int col = wn * 64 + ni * 16 + m16;
                float v = acc[mi][ni][r];
                if (ADD_BIAS) v += bias[col];
                if (HALF_OUT) ((__half*)Cv)[(size_t)row * HID + col] = __float2half(v);
                else          ((float*)Cv)[(size_t)row * HID + col] = v;
            }
        }
    }
}

template <bool A_F32, bool ADD_BIAS, bool HALF_OUT>
__global__ __launch_bounds__(512, 4) void k_mgemm(const void* __restrict__ Av, int strideA, int KA,
                                                  const void* __restrict__ A2v, int strideA2,
                                                  const __half* __restrict__ Bt,
                                                  const float* __restrict__ bias,
                                                  void* Cv, int M, int K) {
    gemm_body<A_F32, ADD_BIAS, HALF_OUT>(blockIdx.x, Av, strideA, KA, A2v, strideA2,
                                         Bt, bias, Cv, M, K);
}

// ---------------------------------------------------------------------------
// Fused scatter + layer-1 GEMM, round-8 schedule fix.
// Round-7 post-mortem: GEMM blocks first in the grid filled all 512 resident
// slots (2 blocks/CU, LDS-limited) for ~24 us before any scatter ran ->
// serialization (78 us = 54 + 24). Fix: scatter becomes 121 PERSISTENT
// grid-strided blocks at blockIdx 0..120, GEMM at 121..511. 121 + 391 = 512 =
// exact resident capacity, so both phases co-reside from t=0: the fabric-bound
// scatter (~0 VALU/MFMA) runs under the GEMM's compute. Each scatter thread
// handles 4 consecutive edges per sweep -> 4 independent atomics+stores in
// flight; 62k threads x 4-deep saturates the ~1 TB/s sector-write ceiling.
// Branch is uniform per block (on blockIdx), so gemm_body's barriers are safe.
// ---------------------------------------------------------------------------
#define SCAT_BLKS 121
__global__ __launch_bounds__(512, 4) void k_scatgemm(
        const unsigned int* __restrict__ ew, const int* __restrict__ mode_p,
        int* __restrict__ cursor, int* __restrict__ csr, int e,
        const float* __restrict__ x, const float* __restrict__ rni,
        const __half* __restrict__ W1t, __half* __restrict__ xh, int M, int K) {
    if ((int)blockIdx.x >= SCAT_BLKS) {
        gemm_body<true, false, true>((int)blockIdx.x - SCAT_BLKS, x, D_IN, D_IN, rni, D_RNI,
                                     W1t, nullptr, xh, M, K);
        return;
    }
    const int t0     = (int)blockIdx.x * 512 + (int)threadIdx.x;
    const int stride = SCAT_BLKS * 512 * 4;
    const int mode   = *mode_p;
    for (int i = t0 * 4; i < e; i += stride) {
        if (i + 4 <= e) {
            int s0, s1, s2, s3, d0, d1, d2, d3;
            if (mode) {
                s0 = (int)ew[2 * (size_t)(i + 0)]; d0 = (int)ew[2 * ((size_t)e + i + 0)];
                s1 = (int)ew[2 * (size_t)(i + 1)]; d1 = (int)ew[2 * ((size_t)e + i + 1)];
                s2 = (int)ew[2 * (size_t)(i + 2)]; d2 = (int)ew[2 * ((size_t)e + i + 2)];
                s3 = (int)ew[2 * (size_t)(i + 3)]; d3 = (int)ew[2 * ((size_t)e + i + 3)];
            } else {
                s0 = (int)ew[(size_t)(i + 0)]; d0 = (int)ew[(size_t)e + i + 0];
                s1 = (int)ew[(size_t)(i + 1)]; d1 = (int)ew[(size_t)e + i + 1];
                s2 = (int)ew[(size_t)(i + 2)]; d2 = (int)ew[(size_t)e + i + 2];
                s3 = (int)ew[(size_t)(i + 3)]; d3 = (int)ew[(size_t)e + i + 3];
            }
            int p0 = atomicAdd(&cursor[d0], 1);
            int p1 = atomicAdd(&cursor[d1], 1);
            int p2 = atomicAdd(&cursor[d2], 1);
            int p3 = atomicAdd(&cursor[d3], 1);
            csr[p0] = s0; csr[p1] = s1; csr[p2] = s2; csr[p3] = s3;
        } else {
            for (int j = i; j < e; ++j) {
                int s, d;
                if (mode) { s = (int)ew[2 * (size_t)j]; d = (int)ew[2 * ((size_t)e + j)]; }
                else      { s = (int)ew[(size_t)j];     d = (int)ew[(size_t)e + j]; }
                int pos = atomicAdd(&cursor[d], 1);
                csr[pos] = s;
            }
        }
    }
}

// ---------------------------------------------------------------------------
// Aggregation, wave-per-node, barrier-free (round-0 verified version):
// h[i,c] = relu( sum_e xh[src_e,c]*dis[src]*dis[i] + xh[i,c]*dis[i]^2 + b[c] )
// ~59 us = 218 MB of L2-miss traffic at ~3.7-4 TB/s, the effective ceiling for
// this random-line gather. Rounds 1-2: NT hints / deeper unrolls only ADD
// bytes; dur tracks bytes/3.7TB/s in every variant. Do not touch.
// ---------------------------------------------------------------------------
__global__ __launch_bounds__(256) void k_agg(const __half* __restrict__ xh,
                                             const int* __restrict__ rowptr,
                                             const int* __restrict__ csr,
                                             const float* __restrict__ dis,
                                             const float* __restrict__ bias,
                                             __half* __restrict__ outh, int n) {
    int i = blockIdx.x * 4 + (threadIdx.x >> 6);
    if (i >= n) return;
    int lane = threadIdx.x & 63;
    int c4 = lane * 4;
    float disd = dis[i];
    int e0 = rowptr[i], e1 = rowptr[i + 1];

    float acc0, acc1, acc2, acc3;
    {
        uint2 v = *reinterpret_cast<const uint2*>(&xh[(size_t)i * HID + c4]);
        float2 f0 = __half22float2(*reinterpret_cast<__half2*>(&v.x));
        float2 f1 = __half22float2(*reinterpret_cast<__half2*>(&v.y));
        float ws = disd * disd;
        acc0 = f0.x * ws; acc1 = f0.y * ws; acc2 = f1.x * ws; acc3 = f1.y * ws;
    }

    for (int e = e0; e < e1; e += 64) {
        int cnt = min(64, e1 - e);
        int sreg = 0; float wreg = 0.0f;
        if (lane < cnt) {
            sreg = csr[e + lane];
            wreg = dis[sreg] * disd;
        }
        int j = 0;
        for (; j + 4 <= cnt; j += 4) {
            int   s0 = __shfl(sreg, j + 0), s1 = __shfl(sreg, j + 1);
            int   s2 = __shfl(sreg, j + 2), s3 = __shfl(sreg, j + 3);
            float w0 = __shfl(wreg, j + 0), w1 = __shfl(wreg, j + 1);
            float w2 = __shfl(wreg, j + 2), w3 = __shfl(wreg, j + 3);
            uint2 v0 = *reinterpret_cast<const uint2*>(&xh[(size_t)s0 * HID + c4]);
            uint2 v1 = *reinterpret_cast<const uint2*>(&xh[(size_t)s1 * HID + c4]);
            uint2 v2 = *reinterpret_cast<const uint2*>(&xh[(size_t)s2 * HID + c4]);
            uint2 v3 = *reinterpret_cast<const uint2*>(&xh[(size_t)s3 * HID + c4]);
            float2 a0 = __half22float2(*reinterpret_cast<__half2*>(&v0.x));
            float2 b0 = __half22float2(*reinterpret_cast<__half2*>(&v0.y));
            float2 a1 = __half22float2(*reinterpret_cast<__half2*>(&v1.x));
            float2 b1 = __half22float2(*reinterpret_cast<__half2*>(&v1.y));
            float2 a2 = __half22float2(*reinterpret_cast<__half2*>(&v2.x));
            float2 b2 = __half22float2(*reinterpret_cast<__half2*>(&v2.y));
            float2 a3 = __half22float2(*reinterpret_cast<__half2*>(&v3.x));
            float2 b3 = __half22float2(*reinterpret_cast<__half2*>(&v3.y));
            acc0 = fmaf(a0.x, w0, acc0); acc1 = fmaf(a0.y, w0, acc1);
            acc2 = fmaf(b0.x, w0, acc2); acc3 = fmaf(b0.y, w0, acc3);
            acc0 = fmaf(a1.x, w1, acc0); acc1 = fmaf(a1.y, w1, acc1);
            acc2 = fmaf(b1.x, w1, acc2); acc3 = fmaf(b1.y, w1, acc3);
            acc0 = fmaf(a2.x, w2, acc0); acc1 = fmaf(a2.y, w2, acc1);
            acc2 = fmaf(b2.x, w2, acc2); acc3 = fmaf(b2.y, w2, acc3);
            acc0 = fmaf(a3.x, w3, acc0); acc1 = fmaf(a3.y, w3, acc1);
            acc2 = fmaf(b3.x, w3, acc2); acc3 = fmaf(b3.y, w3, acc3);
        }
        for (; j < cnt; ++j) {
            int   s = __shfl(sreg, j);
            float w = __shfl(wreg, j);
            uint2 v = *reinterpret_cast<const uint2*>(&xh[(size_t)s * HID + c4]);
            float2 a = __half22float2(*reinterpret_cast<__half2*>(&v.x));
            float2 b = __half22float2(*reinterpret_cast<__half2*>(&v.y));
            acc0 = fmaf(a.x, w, acc0); acc1 = fmaf(a.y, w, acc1);
            acc2 = fmaf(b.x, w, acc2); acc3 = fmaf(b.y, w, acc3);
        }
    }

    float4 bb = *reinterpret_cast<const float4*>(&bias[c4]);
    union { __half2 h2[2]; uint2 u; } o;
    o.h2[0] = __floats2half2_rn(fmaxf(acc0 + bb.x, 0.0f), fmaxf(acc1 + bb.y, 0.0f));
    o.h2[1] = __floats2half2_rn(fmaxf(acc2 + bb.z, 0.0f), fmaxf(acc3 + bb.w, 0.0f));
    *reinterpret_cast<uint2*>(&outh[(size_t)i * HID + c4]) = o.u;
}

// ---------------------------------------------------------------------------
extern "C" void kernel_launch(void* const* d_in, const int* in_sizes, int n_in,
                              void* d_out, int out_size, void* d_ws, size_t ws_size,
                              hipStream_t stream) {
    const float* x     = (const float*)d_in[0];
    const float* rni   = (const float*)d_in[1];
    const unsigned int* ew = (const unsigned int*)d_in[2];
    const float* W1    = (const float*)d_in[3];
    const float* b1    = (const float*)d_in[4];
    const float* W2    = (const float*)d_in[5];
    const float* b2    = (const float*)d_in[6];
    const float* W_out = (const float*)d_in[7];
    const float* b_out = (const float*)d_in[8];
    float* out = (float*)d_out;

    const int n  = in_sizes[0] / D_IN;     // 50000
    const int e  = in_sizes[2] / 2;        // 800000
    const int nb = (n + 1023) / 1024;
    const int K1 = D_IN + D_RNI;           // 160

    char* ws = (char*)d_ws;
    size_t off = 0;
    auto carve = [&](size_t bytes) {
        char* p = ws + off;
        off = (off + bytes + 255) & ~(size_t)255;
        return p;
    };
    __half* xh    = (__half*)carve((size_t)n * HID * sizeof(__half));   // 25.6 MB
    __half* h     = (__half*)carve((size_t)n * HID * sizeof(__half));   // 25.6 MB
    __half* W1t   = (__half*)carve((size_t)K1 * HID * sizeof(__half));
    __half* W2t   = (__half*)carve((size_t)HID * HID * sizeof(__half));
    __half* Wot   = (__half*)carve((size_t)HID * HID * sizeof(__half));
    int*   counts = (int*)carve((size_t)n * sizeof(int));
    int*   incl   = (int*)carve((size_t)n * sizeof(int));
    int*   bsum   = (int*)carve((size_t)(nb + 1) * sizeof(int));
    int*   rowptr = (int*)carve((size_t)(n + 1) * sizeof(int));
    int*   cursor = (int*)carve((size_t)n * sizeof(int));
    float* dis    = (float*)carve((size_t)n * sizeof(float));
    int*   csr    = (int*)carve((size_t)e * sizeof(int));
    int*   mode   = (int*)carve(sizeof(int));
    (void)ws_size;

    const int eb = (e + 255) / 256;
    const int gemm_blocks = (n + 127) / 128;     // 391
    const int agg_blocks  = (n + 3) / 4;
    const int TW = K1 * HID + 2 * HID * HID;
    const int prep_blocks = 1 + (TW + n + 255) / 256;

    // --- prep (detect + weight cvt + counts=0) and CSR chain
    k_prep<<<prep_blocks, 256, 0, stream>>>(ew, 2 * e, mode, W1, W1t, W2, W2t, W_out, Wot,
                                            counts, n);
    k_count<<<eb, 256, 0, stream>>>(ew, mode, counts, e);
    k_scan1<<<nb, 1024, 0, stream>>>(counts, incl, bsum, n);
    k_scan3<<<(n + 255) / 256, 256, 0, stream>>>(counts, incl, bsum, rowptr, cursor, dis, n, nb);

    // --- fused: persistent scatter (blocks 0..120) + layer-1 GEMM (121..511)
    k_scatgemm<<<SCAT_BLKS + gemm_blocks, 512, 0, stream>>>(ew, mode, cursor, csr, e,
                                                            x, rni, W1t, xh, n, K1);
    k_agg<<<agg_blocks, 256, 0, stream>>>(xh, rowptr, csr, dis, b1, h, n);

    // --- layer 2
    k_mgemm<false, false, true><<<gemm_blocks, 512, 0, stream>>>(h, HID, HID, nullptr, 0,
                                                                 W2t, nullptr, xh, n, HID);
    k_agg<<<agg_blocks, 256, 0, stream>>>(xh, rowptr, csr, dis, b2, h, n);

    // --- output layer (fp32 out + bias)
    k_mgemm<false, true, false><<<gemm_blocks, 512, 0, stream>>>(h, HID, HID, nullptr, 0,
                                                                 Wot, b_out, out, n, HID);
}